// Round 3
// baseline (3142.198 us; speedup 1.0000x reference)
//
#include <hip/hip_runtime.h>
#include <hip/hip_fp16.h>

typedef _Float16 f16;
typedef _Float16 half8 __attribute__((ext_vector_type(8)));
typedef _Float16 half4 __attribute__((ext_vector_type(4)));
typedef float f32x4_t __attribute__((ext_vector_type(4)));
typedef unsigned int uint;
typedef unsigned int uint32x4 __attribute__((ext_vector_type(4)));

#define IN_DIM 512
#define H_DIM 1024
#define OUT_DIM 512
#define NBATCH 64
#define NSEQ 512
#define NGROUP 4
#define MB 16      // batch rows per group
#define WPG 16     // workgroups per group (j-split)
#define NJ 64      // j columns per workgroup
#define RING 32    // h ring depth (slack ≫ max wave skew)

// ---------------- f32 -> f16 conversion ----------------
__global__ __launch_bounds__(256) void cvt_f32_f16_k(const float* __restrict__ src,
                                                     f16* __restrict__ dst, int n) {
  int i = (blockIdx.x * 256 + threadIdx.x) * 4;
  if (i + 3 < n) {
    float4 v = *(const float4*)(src + i);
    half4 h;
    h[0] = (f16)v.x; h[1] = (f16)v.y; h[2] = (f16)v.z; h[3] = (f16)v.w;
    *(half4*)(dst + i) = h;
  }
}

__global__ __launch_bounds__(256) void bias_sum_k(const float* __restrict__ a,
                                                  const float* __restrict__ b,
                                                  float* __restrict__ o) {
  int i = blockIdx.x * 256 + threadIdx.x;
  if (i < H_DIM) o[i] = a[i] + b[i];
}

// fill hbuf ring with a pattern that is epoch-invalid for BOTH parities
// (low half LSB=0, high half LSB=1 -> mixed LSBs never produced by real stores)
__global__ __launch_bounds__(256) void fill_pat_k(uint32x4* __restrict__ p, int n4) {
  int i = blockIdx.x * 256 + threadIdx.x;
  uint32x4 v;
  v[0] = 0x0001FFFEu; v[1] = 0x0001FFFEu; v[2] = 0x0001FFFEu; v[3] = 0x0001FFFEu;
  if (i < n4) p[i] = v;
}

// ---------------- xp = x @ W_ih^T + (b_ih + b_hh), stored [S][B][H] f16 ----------------
__global__ __launch_bounds__(256) void xp_gemm_k(
    const float* __restrict__ x, const float* __restrict__ wih,
    const float* __restrict__ bsum, f16* __restrict__ xp2)
{
  __shared__ f16 Alds[128 * 32];
  __shared__ f16 Blds[128 * 32];
  const int tid = threadIdx.x;
  const int l = tid & 63;
  const int w = tid >> 6;
  const int r0 = blockIdx.x * 128;   // rows r = b*512 + s
  const int n0 = blockIdx.y * 128;   // h columns
  const int wm = (w >> 1) << 6;
  const int wn = (w & 1) << 6;
  const int srow = tid >> 1;
  const int scol = (tid & 1) << 4;
  const float* ax = x   + (size_t)(r0 + srow) * IN_DIM + scol;
  const float* bw = wih + (size_t)(n0 + srow) * IN_DIM + scol;
  const uint swz  = (uint)(srow & 7) << 4;
  const uint soff = (uint)srow * 64 + (uint)(tid & 1) * 32;
  char* Ab = (char*)Alds;
  char* Bb = (char*)Blds;

  f32x4_t acc[4][4];
  f32x4_t zv; zv[0] = 0.f; zv[1] = 0.f; zv[2] = 0.f; zv[3] = 0.f;
#pragma unroll
  for (int i = 0; i < 4; ++i)
#pragma unroll
    for (int j = 0; j < 4; ++j) acc[i][j] = zv;

  for (int k0 = 0; k0 < IN_DIM; k0 += 32) {
    float4 a0 = *(const float4*)(ax + k0);
    float4 a1 = *(const float4*)(ax + k0 + 4);
    float4 a2 = *(const float4*)(ax + k0 + 8);
    float4 a3 = *(const float4*)(ax + k0 + 12);
    float4 c0 = *(const float4*)(bw + k0);
    float4 c1 = *(const float4*)(bw + k0 + 4);
    float4 c2 = *(const float4*)(bw + k0 + 8);
    float4 c3 = *(const float4*)(bw + k0 + 12);
    __syncthreads();
    half8 pa0, pa1, pb0, pb1;
    pa0[0]=(f16)a0.x; pa0[1]=(f16)a0.y; pa0[2]=(f16)a0.z; pa0[3]=(f16)a0.w;
    pa0[4]=(f16)a1.x; pa0[5]=(f16)a1.y; pa0[6]=(f16)a1.z; pa0[7]=(f16)a1.w;
    pa1[0]=(f16)a2.x; pa1[1]=(f16)a2.y; pa1[2]=(f16)a2.z; pa1[3]=(f16)a2.w;
    pa1[4]=(f16)a3.x; pa1[5]=(f16)a3.y; pa1[6]=(f16)a3.z; pa1[7]=(f16)a3.w;
    pb0[0]=(f16)c0.x; pb0[1]=(f16)c0.y; pb0[2]=(f16)c0.z; pb0[3]=(f16)c0.w;
    pb0[4]=(f16)c1.x; pb0[5]=(f16)c1.y; pb0[6]=(f16)c1.z; pb0[7]=(f16)c1.w;
    pb1[0]=(f16)c2.x; pb1[1]=(f16)c2.y; pb1[2]=(f16)c2.z; pb1[3]=(f16)c2.w;
    pb1[4]=(f16)c3.x; pb1[5]=(f16)c3.y; pb1[6]=(f16)c3.z; pb1[7]=(f16)c3.w;
    *(half8*)(Ab + (soff ^ swz)) = pa0;
    *(half8*)(Ab + ((soff + 16) ^ swz)) = pa1;
    *(half8*)(Bb + (soff ^ swz)) = pb0;
    *(half8*)(Bb + ((soff + 16) ^ swz)) = pb1;
    __syncthreads();
    half8 af[4], bf[4];
#pragma unroll
    for (int mt = 0; mt < 4; ++mt) {
      uint rr = (uint)(wm + mt * 16 + (l & 15));
      uint off = rr * 64 + ((uint)(l >> 4) << 4);
      af[mt] = *(const half8*)(Ab + (off ^ ((rr & 7) << 4)));
    }
#pragma unroll
    for (int nt = 0; nt < 4; ++nt) {
      uint rr = (uint)(wn + nt * 16 + (l & 15));
      uint off = rr * 64 + ((uint)(l >> 4) << 4);
      bf[nt] = *(const half8*)(Bb + (off ^ ((rr & 7) << 4)));
    }
#pragma unroll
    for (int mt = 0; mt < 4; ++mt)
#pragma unroll
      for (int nt = 0; nt < 4; ++nt)
        acc[mt][nt] = __builtin_amdgcn_mfma_f32_16x16x32_f16(af[mt], bf[nt], acc[mt][nt], 0, 0, 0);
  }

#pragma unroll
  for (int nt = 0; nt < 4; ++nt) {
    const int n = n0 + wn + nt * 16 + (l & 15);
    const float bv = bsum[n];
#pragma unroll
    for (int mt = 0; mt < 4; ++mt) {
#pragma unroll
      for (int i = 0; i < 4; ++i) {
        int r = r0 + wm + mt * 16 + ((l >> 4) << 2) + i;
        int s = r & (NSEQ - 1);
        int b = r >> 9;
        xp2[((size_t)s * NBATCH + b) * H_DIM + n] = (f16)(acc[mt][nt][i] + bv);
      }
    }
  }
}

// ---------------- persistent recurrent scan (self-validating ring, barrier-free) ----------------
// 64 WGs = 4 groups x 16 j-slices; each wave holds its 16x1024 f16 W_hh slice in
// 128 VGPRs, pulls its MFMA A-fragments of h directly from L3 (sc0 sc1, no LDS),
// validates via a per-f16 epoch LSB (parity of t>>5), and stores h + a hint flag
// with NO waits of any kind. Ring depth 32; consumer's own "flags>=t" poll
// subsumes write-after-read backpressure (30-step slack).
__global__ __launch_bounds__(256, 1) void rnn_scan_k(
    const f16* __restrict__ whh2, const f16* __restrict__ xp2,
    f16* __restrict__ hbuf, uint* __restrict__ flags)
{
  const int tid = threadIdx.x;
  const int l   = tid & 63;
  const int w   = tid >> 6;
  const int bid = blockIdx.x;        // 0..63
  const int xcd = bid & 7;
  const int g    = xcd >> 1;                       // batch group 0..3
  const int slot = ((bid >> 3) << 1) | (xcd & 1);  // j-slice 0..15
  const int j0   = slot * NJ + w * 16;             // wave's global j base
  const int c     = l & 15;                        // output col within 16
  const int brow0 = (l >> 4) << 2;                 // output row base

  // persistent W fragments: lane l row (j0+c), k = kt*32 + 8*(l>>4) + e
  half8 wf[32];
  {
    const f16* wp = whh2 + (size_t)(j0 + c) * H_DIM + ((l >> 4) << 3);
#pragma unroll
    for (int kt = 0; kt < 32; ++kt) wf[kt] = *(const half8*)(wp + kt * 32);
  }

  f16* gbase = hbuf + (size_t)g * (RING * MB * H_DIM);
  uint* gflags = flags + g * 64;                   // 64 wave-flags per group
  const int myflag = slot * 4 + w;
  // A-fragment byte offset within a ring slot: row c, k-chunk (l>>4)*8 halves
  const uint frag_off = (uint)c * (H_DIM * 2) + ((uint)(l >> 4) << 4);

  for (int t = 0; t < NSEQ; ++t) {
    // xp_t prefetch (plain cached loads; drain under the flag poll)
    const f16* xpb = xp2 + ((size_t)t * NBATCH + g * MB + brow0) * H_DIM + (j0 + c);
    f16 x0 = xpb[0];
    f16 x1 = xpb[H_DIM];
    f16 x2 = xpb[2 * H_DIM];
    f16 x3 = xpb[3 * H_DIM];

    f32x4_t acc0, acc1, acc2, acc3;
    acc0[0] = (float)x0; acc0[1] = (float)x1; acc0[2] = (float)x2; acc0[3] = (float)x3;
#pragma unroll
    for (int i = 0; i < 4; ++i) { acc1[i] = 0.f; acc2[i] = 0.f; acc3[i] = 0.f; }

    if (t > 0) {
      // hint poll (cheap; data correctness does NOT depend on it)
      while (true) {
        uint v = __hip_atomic_load(&gflags[l], __ATOMIC_RELAXED, __HIP_MEMORY_SCOPE_AGENT);
        if (__all((int)(v >= (uint)t))) break;
      }
      const char* sbase = (const char*)gbase
                        + (size_t)(t & (RING - 1)) * (MB * H_DIM * 2) + frag_off;
      const uint pexp = ((t >> 5) & 1) ? 0x00010001u : 0u;
      uint32x4 sv[32];
      for (;;) {
        // pull 32 A-fragments straight from L3 (bypass L1/L2)
#pragma unroll
        for (int kt = 0; kt < 32; ++kt)
          asm volatile("global_load_dwordx4 %0, %1, off offset:%2 sc0 sc1"
                       : "=v"(sv[kt]) : "v"(sbase), "i"(kt * 64) : "memory");
        asm volatile("s_waitcnt vmcnt(0)" ::: "memory");
        // epoch validation: every f16's LSB must equal parity(t>>5)
        uint bad;
        if (pexp) {
          uint a = 0xFFFFFFFFu;
#pragma unroll
          for (int kt = 0; kt < 32; ++kt) a &= sv[kt][0] & sv[kt][1] & sv[kt][2] & sv[kt][3];
          bad = ~a & 0x00010001u;
        } else {
          uint o = 0u;
#pragma unroll
          for (int kt = 0; kt < 32; ++kt) o |= sv[kt][0] | sv[kt][1] | sv[kt][2] | sv[kt][3];
          bad = o & 0x00010001u;
        }
        if (!__any((int)(bad != 0u))) break;   // all data present & current
      }
      // h_t @ W^T, 4 independent accumulator chains
#pragma unroll
      for (int kt = 0; kt < 32; kt += 4) {
        acc0 = __builtin_amdgcn_mfma_f32_16x16x32_f16(__builtin_bit_cast(half8, sv[kt + 0]), wf[kt + 0], acc0, 0, 0, 0);
        acc1 = __builtin_amdgcn_mfma_f32_16x16x32_f16(__builtin_bit_cast(half8, sv[kt + 1]), wf[kt + 1], acc1, 0, 0, 0);
        acc2 = __builtin_amdgcn_mfma_f32_16x16x32_f16(__builtin_bit_cast(half8, sv[kt + 2]), wf[kt + 2], acc2, 0, 0, 0);
        acc3 = __builtin_amdgcn_mfma_f32_16x16x32_f16(__builtin_bit_cast(half8, sv[kt + 3]), wf[kt + 3], acc3, 0, 0, 0);
      }
    }
    // t == 0: h0 = 0 -> h1 = tanh(xp_0)

    f32x4_t accs = (acc0 + acc1) + (acc2 + acc3);

    // tanh, force epoch LSB, pack f16 pairs, store (relaxed, no waits)
    const uint pnew = (((t + 1) >> 5) & 1) ? 1u : 0u;
    uint st[4];
#pragma unroll
    for (int i = 0; i < 4; ++i) {
      float pre = accs[i];
      float e = __expf(2.0f * pre);
      float th = 1.0f - 2.0f / (e + 1.0f);
      f16 hf = (f16)th;
      uint hb = (uint)__builtin_bit_cast(unsigned short, hf);
      hb = (hb & 0xFFFEu) | pnew;
      uint pv = __shfl_xor(hb, 1, 64);
      st[i] = hb | (pv << 16);           // valid on even-c lanes: (c, c+1)
    }
    uint* nb = (uint*)((char*)gbase + (size_t)((t + 1) & (RING - 1)) * (MB * H_DIM * 2));
    if ((c & 1) == 0) {
#pragma unroll
      for (int i = 0; i < 4; ++i) {
        uint idx = (uint)(brow0 + i) * (H_DIM / 2) + (uint)((j0 + c) >> 1);
        __hip_atomic_store(nb + idx, st[i], __ATOMIC_RELAXED, __HIP_MEMORY_SCOPE_AGENT);
      }
    }
    if (l == 0)
      __hip_atomic_store(&gflags[myflag], (uint)(t + 1), __ATOMIC_RELAXED, __HIP_MEMORY_SCOPE_AGENT);
  }
}

// ---------------- out = h_final @ W_fc^T + b_fc ----------------
__global__ __launch_bounds__(64) void fc_out_k(
    const f16* __restrict__ hbuf, const f16* __restrict__ wfc2,
    const float* __restrict__ bfc, float* __restrict__ out)
{
  const int l = threadIdx.x;
  const int wg = blockIdx.x;            // 0..127
  const int m0 = wg & 3;                // batch group
  const int n0 = (wg >> 2) << 4;        // output col base
  // h_512 lives in ring slot 512 % RING == 0
  const f16* ap = hbuf + (size_t)m0 * (RING * MB * H_DIM)
                  + (size_t)(l & 15) * H_DIM + ((l >> 4) << 3);
  const f16* bp = wfc2 + (size_t)(n0 + (l & 15)) * H_DIM + ((l >> 4) << 3);
  f32x4_t acc;
  float bv = bfc[n0 + (l & 15)];
  acc[0] = bv; acc[1] = bv; acc[2] = bv; acc[3] = bv;
#pragma unroll
  for (int kt = 0; kt < 32; ++kt) {
    half8 a = *(const half8*)(ap + kt * 32);
    half8 b = *(const half8*)(bp + kt * 32);
    acc = __builtin_amdgcn_mfma_f32_16x16x32_f16(a, b, acc, 0, 0, 0);
  }
  const int b0 = (m0 << 4) + ((l >> 4) << 2);
  const int o  = n0 + (l & 15);
#pragma unroll
  for (int i = 0; i < 4; ++i) out[(size_t)(b0 + i) * OUT_DIM + o] = acc[i];
}

// ---------------- launch ----------------
extern "C" void kernel_launch(void* const* d_in, const int* in_sizes, int n_in,
                              void* d_out, int out_size, void* d_ws, size_t ws_size,
                              hipStream_t stream) {
  const float* x   = (const float*)d_in[0];
  const float* wih = (const float*)d_in[1];
  const float* whh = (const float*)d_in[2];
  const float* bih = (const float*)d_in[3];
  const float* bhh = (const float*)d_in[4];
  const float* wfc = (const float*)d_in[5];
  const float* bfc = (const float*)d_in[6];
  float* out = (float*)d_out;
  char* ws = (char*)d_ws;

  // workspace layout (~71.1 MB total)
  f16*   xp2  = (f16*)(ws);                                  // 64 MB  [S][B][H] f16
  f16*   whh2 = (f16*)(ws + (size_t)(64 << 20));             // 2 MB
  f16*   wfc2 = (f16*)(ws + (size_t)(66 << 20));             // 1 MB
  float* bsum = (float*)(ws + (size_t)(67 << 20));           // 4 KB
  f16*   hbuf = (f16*)(ws + (size_t)(67 << 20) + 65536);     // 4 MB [4][RING][16][1024]
  uint*  flags= (uint*)(ws + (size_t)(67 << 20) + 65536 + (4 << 20)); // 1 KB [4][64]

  hipMemsetAsync(flags, 0, 1024, stream);
  // fill h ring with both-parity-invalid pattern (fresh every call)
  hipLaunchKernelGGL(fill_pat_k, dim3(1024), dim3(256), 0, stream,
                     (uint32x4*)hbuf, (4 << 20) / 16);

  hipLaunchKernelGGL(cvt_f32_f16_k, dim3(1024), dim3(256), 0, stream, whh, whh2, H_DIM * H_DIM);
  hipLaunchKernelGGL(cvt_f32_f16_k, dim3(512),  dim3(256), 0, stream, wfc, wfc2, OUT_DIM * H_DIM);
  hipLaunchKernelGGL(bias_sum_k,    dim3(4),    dim3(256), 0, stream, bih, bhh, bsum);
  hipLaunchKernelGGL(xp_gemm_k,     dim3(256, 8), dim3(256), 0, stream, x, wih, bsum, xp2);
  hipLaunchKernelGGL(rnn_scan_k,    dim3(64),   dim3(256), 0, stream, whh2, xp2, hbuf, flags);
  hipLaunchKernelGGL(fc_out_k,      dim3(128),  dim3(64),  0, stream, hbuf, wfc2, bfc, out);
}

// Round 4
// 1548.567 us; speedup vs baseline: 2.0291x; 2.0291x over previous
//
#include <hip/hip_runtime.h>
#include <hip/hip_fp16.h>

typedef _Float16 f16;
typedef _Float16 half8 __attribute__((ext_vector_type(8)));
typedef _Float16 half4 __attribute__((ext_vector_type(4)));
typedef float f32x4_t __attribute__((ext_vector_type(4)));
typedef unsigned int uint;
typedef unsigned int uint32x4 __attribute__((ext_vector_type(4)));

#define IN_DIM 512
#define H_DIM 1024
#define OUT_DIM 512
#define NBATCH 64
#define NSEQ 512
#define NGROUP 4
#define MB 16      // batch rows per group
#define WPG 16     // workgroups per group (j-split)
#define NJ 64      // j columns per workgroup
#define RING 4     // h ring depth (max WG skew within a group is 1 step)

// ---------------- f32 -> f16 conversion ----------------
__global__ __launch_bounds__(256) void cvt_f32_f16_k(const float* __restrict__ src,
                                                     f16* __restrict__ dst, int n) {
  int i = (blockIdx.x * 256 + threadIdx.x) * 4;
  if (i + 3 < n) {
    float4 v = *(const float4*)(src + i);
    half4 h;
    h[0] = (f16)v.x; h[1] = (f16)v.y; h[2] = (f16)v.z; h[3] = (f16)v.w;
    *(half4*)(dst + i) = h;
  }
}

__global__ __launch_bounds__(256) void bias_sum_k(const float* __restrict__ a,
                                                  const float* __restrict__ b,
                                                  float* __restrict__ o) {
  int i = blockIdx.x * 256 + threadIdx.x;
  if (i < H_DIM) o[i] = a[i] + b[i];
}

// fill hbuf ring with a pattern that is epoch-invalid for BOTH parities
// (low-half LSB=0, high-half LSB=1 -> never produced by real stores)
__global__ __launch_bounds__(256) void fill_pat_k(uint32x4* __restrict__ p, int n4) {
  int i = blockIdx.x * 256 + threadIdx.x;
  uint32x4 v;
  v[0] = 0x0001FFFEu; v[1] = 0x0001FFFEu; v[2] = 0x0001FFFEu; v[3] = 0x0001FFFEu;
  if (i < n4) p[i] = v;
}

// ---------------- xp = x @ W_ih^T + (b_ih + b_hh), stored [S][B][H] f16 ----------------
__global__ __launch_bounds__(256) void xp_gemm_k(
    const float* __restrict__ x, const float* __restrict__ wih,
    const float* __restrict__ bsum, f16* __restrict__ xp2)
{
  __shared__ f16 Alds[128 * 32];
  __shared__ f16 Blds[128 * 32];
  const int tid = threadIdx.x;
  const int l = tid & 63;
  const int w = tid >> 6;
  const int r0 = blockIdx.x * 128;   // rows r = b*512 + s
  const int n0 = blockIdx.y * 128;   // h columns
  const int wm = (w >> 1) << 6;
  const int wn = (w & 1) << 6;
  const int srow = tid >> 1;
  const int scol = (tid & 1) << 4;
  const float* ax = x   + (size_t)(r0 + srow) * IN_DIM + scol;
  const float* bw = wih + (size_t)(n0 + srow) * IN_DIM + scol;
  const uint swz  = (uint)(srow & 7) << 4;
  const uint soff = (uint)srow * 64 + (uint)(tid & 1) * 32;
  char* Ab = (char*)Alds;
  char* Bb = (char*)Blds;

  f32x4_t acc[4][4];
  f32x4_t zv; zv[0] = 0.f; zv[1] = 0.f; zv[2] = 0.f; zv[3] = 0.f;
#pragma unroll
  for (int i = 0; i < 4; ++i)
#pragma unroll
    for (int j = 0; j < 4; ++j) acc[i][j] = zv;

  for (int k0 = 0; k0 < IN_DIM; k0 += 32) {
    float4 a0 = *(const float4*)(ax + k0);
    float4 a1 = *(const float4*)(ax + k0 + 4);
    float4 a2 = *(const float4*)(ax + k0 + 8);
    float4 a3 = *(const float4*)(ax + k0 + 12);
    float4 c0 = *(const float4*)(bw + k0);
    float4 c1 = *(const float4*)(bw + k0 + 4);
    float4 c2 = *(const float4*)(bw + k0 + 8);
    float4 c3 = *(const float4*)(bw + k0 + 12);
    __syncthreads();
    half8 pa0, pa1, pb0, pb1;
    pa0[0]=(f16)a0.x; pa0[1]=(f16)a0.y; pa0[2]=(f16)a0.z; pa0[3]=(f16)a0.w;
    pa0[4]=(f16)a1.x; pa0[5]=(f16)a1.y; pa0[6]=(f16)a1.z; pa0[7]=(f16)a1.w;
    pa1[0]=(f16)a2.x; pa1[1]=(f16)a2.y; pa1[2]=(f16)a2.z; pa1[3]=(f16)a2.w;
    pa1[4]=(f16)a3.x; pa1[5]=(f16)a3.y; pa1[6]=(f16)a3.z; pa1[7]=(f16)a3.w;
    pb0[0]=(f16)c0.x; pb0[1]=(f16)c0.y; pb0[2]=(f16)c0.z; pb0[3]=(f16)c0.w;
    pb0[4]=(f16)c1.x; pb0[5]=(f16)c1.y; pb0[6]=(f16)c1.z; pb0[7]=(f16)c1.w;
    pb1[0]=(f16)c2.x; pb1[1]=(f16)c2.y; pb1[2]=(f16)c2.z; pb1[3]=(f16)c2.w;
    pb1[4]=(f16)c3.x; pb1[5]=(f16)c3.y; pb1[6]=(f16)c3.z; pb1[7]=(f16)c3.w;
    *(half8*)(Ab + (soff ^ swz)) = pa0;
    *(half8*)(Ab + ((soff + 16) ^ swz)) = pa1;
    *(half8*)(Bb + (soff ^ swz)) = pb0;
    *(half8*)(Bb + ((soff + 16) ^ swz)) = pb1;
    __syncthreads();
    half8 af[4], bf[4];
#pragma unroll
    for (int mt = 0; mt < 4; ++mt) {
      uint rr = (uint)(wm + mt * 16 + (l & 15));
      uint off = rr * 64 + ((uint)(l >> 4) << 4);
      af[mt] = *(const half8*)(Ab + (off ^ ((rr & 7) << 4)));
    }
#pragma unroll
    for (int nt = 0; nt < 4; ++nt) {
      uint rr = (uint)(wn + nt * 16 + (l & 15));
      uint off = rr * 64 + ((uint)(l >> 4) << 4);
      bf[nt] = *(const half8*)(Bb + (off ^ ((rr & 7) << 4)));
    }
#pragma unroll
    for (int mt = 0; mt < 4; ++mt)
#pragma unroll
      for (int nt = 0; nt < 4; ++nt)
        acc[mt][nt] = __builtin_amdgcn_mfma_f32_16x16x32_f16(af[mt], bf[nt], acc[mt][nt], 0, 0, 0);
  }

#pragma unroll
  for (int nt = 0; nt < 4; ++nt) {
    const int n = n0 + wn + nt * 16 + (l & 15);
    const float bv = bsum[n];
#pragma unroll
    for (int mt = 0; mt < 4; ++mt) {
#pragma unroll
      for (int i = 0; i < 4; ++i) {
        int r = r0 + wm + mt * 16 + ((l >> 4) << 2) + i;
        int s = r & (NSEQ - 1);
        int b = r >> 9;
        xp2[((size_t)s * NBATCH + b) * H_DIM + n] = (f16)(acc[mt][nt][i] + bv);
      }
    }
  }
}

// ---------------- persistent recurrent scan ----------------
// 64 WGs = 4 groups x 16 j-slices. K-SPLIT: wave w of a WG computes partial
// sums over k in [w*256,(w+1)*256) for all 64 j of the WG; W slice (64j x 256k
// f16 = 128 VGPR) pinned register-resident. The wave's A-operand is only 8 KB
// of h (128 B/lane, 8 loads at immediate offsets) pulled directly from L3 with
// sc0 sc1; data self-validates via a per-f16 epoch LSB (parity of t>>2), so
// producers store with NO drain and NO flags. Ring-4 h buffers (WG skew <= 1
// step by construction). One __syncthreads per step (cross-wave K-reduction
// in padded LDS).
__global__ __launch_bounds__(256, 1) void rnn_scan_k(
    const f16* __restrict__ whh2, const f16* __restrict__ xp2,
    f16* __restrict__ hbuf)
{
  __shared__ float plds[4][4][16][20];   // [wave][jtile][row][col+pad] = 20 KB
  const int tid = threadIdx.x;
  const int l   = tid & 63;
  const int w   = tid >> 6;
  const int bid = blockIdx.x;        // 0..63
  const int xcd = bid & 7;
  const int g    = xcd >> 1;                       // batch group 0..3
  const int slot = ((bid >> 3) << 1) | (xcd & 1);  // j-slice 0..15
  const int c     = l & 15;
  const int brow0 = (l >> 4) << 2;                 // batch-row base
  const int j0    = slot * NJ + w * 16;            // wave's epilogue j-tile

  // W fragments: wf[jt][kt] row j = slot*64 + jt*16 + c,
  //              k = w*256 + kt*32 + (l>>4)*8 + e   -> 128 VGPRs, pinned
  half8 wf[4][8];
  {
    const f16* wp = whh2 + (size_t)(slot * NJ + c) * H_DIM + w * 256 + ((l >> 4) << 3);
#pragma unroll
    for (int jt = 0; jt < 4; ++jt)
#pragma unroll
      for (int kt = 0; kt < 8; ++kt)
        wf[jt][kt] = *(const half8*)(wp + (size_t)jt * 16 * H_DIM + kt * 32);
#pragma unroll
    for (int jt = 0; jt < 4; ++jt)
#pragma unroll
      for (int kt = 0; kt < 8; ++kt)
        asm volatile("" : "+v"(wf[jt][kt]));      // pin: no remat, stay in VGPRs
  }

  f16* gbase = hbuf + (size_t)g * (RING * MB * H_DIM);
  // per-lane spin-load base: row c, k-quarter w, chunk (l>>4)
  const uint frag_off = (uint)c * (H_DIM * 2) + (uint)w * 512 + ((uint)(l >> 4) << 4);

  for (int t = 0; t < NSEQ; ++t) {
    // xp_t prefetch (plain cached loads; overlap with spin)
    const f16* xpb = xp2 + ((size_t)t * NBATCH + g * MB + brow0) * H_DIM + (j0 + c);
    f16 x0 = xpb[0];
    f16 x1 = xpb[H_DIM];
    f16 x2 = xpb[2 * H_DIM];
    f16 x3 = xpb[3 * H_DIM];

    f32x4_t acc[4];
#pragma unroll
    for (int jt = 0; jt < 4; ++jt) { acc[jt][0]=0.f; acc[jt][1]=0.f; acc[jt][2]=0.f; acc[jt][3]=0.f; }

    if (t > 0) {
      const char* sbase = (const char*)gbase
                        + (size_t)(t & (RING - 1)) * (MB * H_DIM * 2) + frag_off;
      const uint pexp = ((t >> 2) & 1) ? 0x00010001u : 0u;
      uint32x4 sv[8];
      // per-lane spin: the poll IS the data load (self-validating epoch LSBs)
      for (;;) {
#pragma unroll
        for (int kt = 0; kt < 8; ++kt)
          asm volatile("global_load_dwordx4 %0, %1, off offset:%2 sc0 sc1"
                       : "=v"(sv[kt]) : "v"(sbase), "i"(kt * 64) : "memory");
        asm volatile("s_waitcnt vmcnt(0)" ::: "memory");
        __builtin_amdgcn_sched_barrier(0);
        uint a = 0xFFFFFFFFu, o = 0u;
#pragma unroll
        for (int kt = 0; kt < 8; ++kt) {
          a &= sv[kt][0] & sv[kt][1] & sv[kt][2] & sv[kt][3];
          o |= sv[kt][0] | sv[kt][1] | sv[kt][2] | sv[kt][3];
        }
        uint bad = pexp ? (~a & 0x00010001u) : (o & 0x00010001u);
        if (!bad) break;
      }
      // partial h_t @ W^T over this wave's k-quarter: 4 j-chains of depth 8
#pragma unroll
      for (int kt = 0; kt < 8; ++kt) {
        half8 af = __builtin_bit_cast(half8, sv[kt]);
        acc[0] = __builtin_amdgcn_mfma_f32_16x16x32_f16(af, wf[0][kt], acc[0], 0, 0, 0);
        acc[1] = __builtin_amdgcn_mfma_f32_16x16x32_f16(af, wf[1][kt], acc[1], 0, 0, 0);
        acc[2] = __builtin_amdgcn_mfma_f32_16x16x32_f16(af, wf[2][kt], acc[2], 0, 0, 0);
        acc[3] = __builtin_amdgcn_mfma_f32_16x16x32_f16(af, wf[3][kt], acc[3], 0, 0, 0);
      }
    }
    // t == 0: h0 = 0 -> partials are zero; h1 = tanh(xp_0)

    // cross-wave K-reduction via LDS (padded: 4-row group stride 80 dw -> 2-way free)
#pragma unroll
    for (int jt = 0; jt < 4; ++jt)
#pragma unroll
      for (int i = 0; i < 4; ++i)
        plds[w][jt][brow0 + i][c] = acc[jt][i];
    __syncthreads();

    const uint pnew = (((t + 1) >> 2) & 1) ? 1u : 0u;
    uint* nb = (uint*)((char*)gbase + (size_t)((t + 1) & (RING - 1)) * (MB * H_DIM * 2));
    uint st[4];
#pragma unroll
    for (int i = 0; i < 4; ++i) {
      float s = plds[0][w][brow0 + i][c] + plds[1][w][brow0 + i][c]
              + plds[2][w][brow0 + i][c] + plds[3][w][brow0 + i][c];
      float xi = (i == 0) ? (float)x0 : (i == 1) ? (float)x1 : (i == 2) ? (float)x2 : (float)x3;
      float pre = s + xi;
      float e = __expf(2.0f * pre);
      float th = 1.0f - 2.0f / (e + 1.0f);
      f16 hf = (f16)th;
      uint hb = (uint)__builtin_bit_cast(unsigned short, hf);
      hb = (hb & 0xFFFEu) | pnew;
      uint pv = __shfl_xor(hb, 1, 64);
      st[i] = hb | (pv << 16);           // valid on even-c lanes: cols (c, c+1)
    }
    if ((c & 1) == 0) {
#pragma unroll
      for (int i = 0; i < 4; ++i) {
        uint idx = (uint)(brow0 + i) * (H_DIM / 2) + (uint)((j0 + c) >> 1);
        __hip_atomic_store(nb + idx, st[i], __ATOMIC_RELAXED, __HIP_MEMORY_SCOPE_AGENT);
      }
    }
    // no drain, no flag: consumers validate the data itself
  }
}

// ---------------- out = h_final @ W_fc^T + b_fc ----------------
__global__ __launch_bounds__(64) void fc_out_k(
    const f16* __restrict__ hbuf, const f16* __restrict__ wfc2,
    const float* __restrict__ bfc, float* __restrict__ out)
{
  const int l = threadIdx.x;
  const int wg = blockIdx.x;            // 0..127
  const int m0 = wg & 3;                // batch group
  const int n0 = (wg >> 2) << 4;        // output col base
  // h_512 lives in ring slot 512 % RING == 0
  const f16* ap = hbuf + (size_t)m0 * (RING * MB * H_DIM)
                  + (size_t)(l & 15) * H_DIM + ((l >> 4) << 3);
  const f16* bp = wfc2 + (size_t)(n0 + (l & 15)) * H_DIM + ((l >> 4) << 3);
  f32x4_t acc;
  float bv = bfc[n0 + (l & 15)];
  acc[0] = bv; acc[1] = bv; acc[2] = bv; acc[3] = bv;
#pragma unroll
  for (int kt = 0; kt < 32; ++kt) {
    half8 a = *(const half8*)(ap + kt * 32);
    half8 b = *(const half8*)(bp + kt * 32);
    acc = __builtin_amdgcn_mfma_f32_16x16x32_f16(a, b, acc, 0, 0, 0);
  }
  const int b0 = (m0 << 4) + ((l >> 4) << 2);
  const int o  = n0 + (l & 15);
#pragma unroll
  for (int i = 0; i < 4; ++i) out[(size_t)(b0 + i) * OUT_DIM + o] = acc[i];
}

// ---------------- launch ----------------
extern "C" void kernel_launch(void* const* d_in, const int* in_sizes, int n_in,
                              void* d_out, int out_size, void* d_ws, size_t ws_size,
                              hipStream_t stream) {
  const float* x   = (const float*)d_in[0];
  const float* wih = (const float*)d_in[1];
  const float* whh = (const float*)d_in[2];
  const float* bih = (const float*)d_in[3];
  const float* bhh = (const float*)d_in[4];
  const float* wfc = (const float*)d_in[5];
  const float* bfc = (const float*)d_in[6];
  float* out = (float*)d_out;
  char* ws = (char*)d_ws;

  // workspace layout (~67.6 MB total)
  f16*   xp2  = (f16*)(ws);                                  // 64 MB  [S][B][H] f16
  f16*   whh2 = (f16*)(ws + (size_t)(64 << 20));             // 2 MB
  f16*   wfc2 = (f16*)(ws + (size_t)(66 << 20));             // 1 MB
  float* bsum = (float*)(ws + (size_t)(67 << 20));           // 4 KB
  f16*   hbuf = (f16*)(ws + (size_t)(67 << 20) + 65536);     // 512 KB [4][RING=4][16][1024]

  // fill h ring with both-parity-invalid pattern (fresh every call)
  hipLaunchKernelGGL(fill_pat_k, dim3(128), dim3(256), 0, stream,
                     (uint32x4*)hbuf, (512 << 10) / 16);

  hipLaunchKernelGGL(cvt_f32_f16_k, dim3(1024), dim3(256), 0, stream, whh, whh2, H_DIM * H_DIM);
  hipLaunchKernelGGL(cvt_f32_f16_k, dim3(512),  dim3(256), 0, stream, wfc, wfc2, OUT_DIM * H_DIM);
  hipLaunchKernelGGL(bias_sum_k,    dim3(4),    dim3(256), 0, stream, bih, bhh, bsum);
  hipLaunchKernelGGL(xp_gemm_k,     dim3(256, 8), dim3(256), 0, stream, x, wih, bsum, xp2);
  hipLaunchKernelGGL(rnn_scan_k,    dim3(64),   dim3(256), 0, stream, whh2, xp2, hbuf);
  hipLaunchKernelGGL(fc_out_k,      dim3(128),  dim3(64),  0, stream, hbuf, wfc2, bfc, out);
}